// Round 2
// baseline (305.118 us; speedup 1.0000x reference)
//
#include <hip/hip_runtime.h>

typedef unsigned short u16;
typedef __bf16 bf16x8 __attribute__((ext_vector_type(8)));
typedef float f32x4 __attribute__((ext_vector_type(4)));

#define MFMA(a, b, c) __builtin_amdgcn_mfma_f32_16x16x32_bf16((a), (b), (c), 0, 0, 0)

__device__ __forceinline__ u16 f2bf(float f) {
    unsigned u = __float_as_uint(f);
    unsigned r = (u + 0x7fffu + ((u >> 16) & 1u)) >> 16;  // RNE
    return (u16)r;
}
__device__ __forceinline__ float bf2f(u16 h) { return __uint_as_float(((unsigned)h) << 16); }

// Shapes: b=16, c=256, n=4096, heads=8, dim_head=32.
// qkv ws holds q rows 0..255, k rows 256..511 in (b, o, n); v goes transposed to vT (b, n, d).

// K1: fused LayerNorm + transpose: x (b,c,n) fp32 -> xlnT (b,n,c) bf16. grid 1024.
__global__ __launch_bounds__(256) void k_ln(const float* __restrict__ x,
                                            const float* __restrict__ gamma,
                                            const float* __restrict__ beta,
                                            u16* __restrict__ xlnT) {
    int bid = blockIdx.x;
    int b = bid >> 6, nt = bid & 63;
    int nb = nt * 64;
    __shared__ unsigned xsu[256 * 33];
    __shared__ float muv[64], rsv[64];
    __shared__ float redS[8 * 64], redS2[8 * 64];
    int t = threadIdx.x;
    {
        int np = t & 31;
        int c0 = t >> 5;
        const float* xp = x + ((size_t)b * 256) * 4096 + nb + np * 2;
        for (int i = 0; i < 32; i++) {
            int c = c0 + i * 8;
            float2 f = *(const float2*)(xp + (size_t)c * 4096);
            unsigned u = (unsigned)f2bf(f.x) | ((unsigned)f2bf(f.y) << 16);
            xsu[c * 33 + np] = u;
        }
    }
    __syncthreads();
    {
        int np = t & 31, q = t >> 5;
        float s0 = 0, s20 = 0, s1 = 0, s21 = 0;
        for (int i = 0; i < 32; i++) {
            unsigned u = xsu[(q * 32 + i) * 33 + np];
            float a = bf2f((u16)(u & 0xffffu));
            float bv = bf2f((u16)(u >> 16));
            s0 += a; s20 += a * a; s1 += bv; s21 += bv * bv;
        }
        redS[q * 64 + np * 2] = s0;  redS[q * 64 + np * 2 + 1] = s1;
        redS2[q * 64 + np * 2] = s20; redS2[q * 64 + np * 2 + 1] = s21;
    }
    __syncthreads();
    if (t < 64) {
        float s = 0, s2 = 0;
        for (int q = 0; q < 8; q++) { s += redS[q * 64 + t]; s2 += redS2[q * 64 + t]; }
        float m = s * (1.f / 256.f);
        float var = s2 * (1.f / 256.f) - m * m;
        muv[t] = m;
        rsv[t] = rsqrtf(var + 1e-5f);
    }
    __syncthreads();
    {
        int c4 = (t & 63) * 4;
        int ng = t >> 6;
        float g[4], e[4];
        for (int j = 0; j < 4; j++) { g[j] = gamma[c4 + j]; e[j] = beta[c4 + j]; }
        for (int i = 0; i < 16; i++) {
            int n = ng * 16 + i;
            float m = muv[n], rs = rsv[n];
            u16 h[4];
            for (int j = 0; j < 4; j++) {
                unsigned u = xsu[(c4 + j) * 33 + (n >> 1)];
                u16 raw = (n & 1) ? (u16)(u >> 16) : (u16)(u & 0xffffu);
                float v = (bf2f(raw) - m) * rs * g[j] + e[j];
                h[j] = f2bf(v);
            }
            uint2 w2;
            w2.x = (unsigned)h[0] | ((unsigned)h[1] << 16);
            w2.y = (unsigned)h[2] | ((unsigned)h[3] << 16);
            *(uint2*)(xlnT + ((size_t)(b * 4096 + nb + n)) * 256 + c4) = w2;
        }
    }
}

// K2: weight transposes + zero sims/normsq. grid 768.
__global__ __launch_bounds__(256) void k_prep(const float* __restrict__ Wqkv,
                                              const float* __restrict__ Wout,
                                              u16* __restrict__ WqkvT, u16* __restrict__ WoutT,
                                              float* __restrict__ sims, float* __restrict__ normsq) {
    int i = blockIdx.x * 256 + threadIdx.x;
    if (i < 768 * 256) { int o = i >> 8, c = i & 255; WqkvT[i] = f2bf(Wqkv[c * 768 + o]); }
    if (i < 256 * 256) { int o = i >> 8, c = i & 255; WoutT[i] = f2bf(Wout[c * 256 + o]); }
    if (i < 128 * 1024) sims[i] = 0.f;
    if (i < 16 * 512) normsq[i] = 0.f;
}

// K3: QKV GEMM. A(=WqkvT rows) in registers, B(=xlnT) staged in 2 K-halves.
// mt 0..3 -> q/k rows stored (b,o,n) + normsq atomics; mt 4..5 -> v stored transposed to vT (b,n,d).
// grid = 16*6*32 = 3072
__global__ __launch_bounds__(256, 3) void k_qkv(const u16* __restrict__ WqkvT,
                                                const u16* __restrict__ xlnT,
                                                u16* __restrict__ qkv, u16* __restrict__ vT,
                                                float* __restrict__ normsq) {
    int bid = blockIdx.x;
    int b = bid / 192, r0 = bid % 192;
    int mt = r0 >> 5, nt = r0 & 31;
    int mbase = mt * 128, nbase = nt * 128;
    __shared__ __align__(16) u16 smem[128 * 136];  // 34.8 KB; row stride 272B = 17x16 (odd) -> conflict-free b128
    int t = threadIdx.x, w = t >> 6, lane = t & 63, l15 = lane & 15, quad = lane >> 4;
    // A preload: wave rows mbase + w*32 .. +63 (2 fm of 16), full K=256
    bf16x8 afr[2][8];
#pragma unroll
    for (int fm = 0; fm < 2; fm++)
#pragma unroll
        for (int kt = 0; kt < 8; kt++)
            afr[fm][kt] = *(const bf16x8*)(WqkvT + (size_t)(mbase + w * 32 + fm * 16 + l15) * 256 + kt * 32 + quad * 8);
    f32x4 acc[2][8];
    f32x4 z = {0.f, 0.f, 0.f, 0.f};
#pragma unroll
    for (int fm = 0; fm < 2; fm++)
#pragma unroll
        for (int fn = 0; fn < 8; fn++) acc[fm][fn] = z;
    const u16* Bp = xlnT + ((size_t)b * 4096 + nbase) * 256;
    int srow = t >> 1, sseg = t & 1;
    for (int h = 0; h < 2; h++) {
        if (h) __syncthreads();
        // stage K-half: 128 rows x 128 k
#pragma unroll
        for (int g = 0; g < 2; g++) {
            uint4 ld[4];
#pragma unroll
            for (int i = 0; i < 4; i++)
                ld[i] = *(const uint4*)(Bp + (size_t)srow * 256 + h * 128 + sseg * 64 + g * 32 + i * 8);
#pragma unroll
            for (int i = 0; i < 4; i++)
                *(uint4*)&smem[srow * 136 + sseg * 64 + g * 32 + i * 8] = ld[i];
        }
        __syncthreads();
#pragma unroll
        for (int ktl = 0; ktl < 4; ktl++) {
            int kt = h * 4 + ktl;
#pragma unroll
            for (int fn = 0; fn < 8; fn++) {
                bf16x8 bfr = *(const bf16x8*)&smem[(fn * 16 + l15) * 136 + ktl * 32 + quad * 8];
                acc[0][fn] = MFMA(afr[0][kt], bfr, acc[0][fn]);
                acc[1][fn] = MFMA(afr[1][kt], bfr, acc[1][fn]);
            }
        }
    }
    __syncthreads();
    if (mt < 4) {
        // per-row sumsq (fp32 acc) -> normsq atomics
#pragma unroll
        for (int fm = 0; fm < 2; fm++)
#pragma unroll
            for (int rr = 0; rr < 4; rr++) {
                float s = 0.f;
#pragma unroll
                for (int fn = 0; fn < 8; fn++) { float v = acc[fm][fn][rr]; s += v * v; }
                s += __shfl_down(s, 8, 16);
                s += __shfl_down(s, 4, 16);
                s += __shfl_down(s, 2, 16);
                s += __shfl_down(s, 1, 16);
                if (l15 == 0)
                    atomicAdd(&normsq[b * 512 + mbase + w * 32 + fm * 16 + quad * 4 + rr], s);
            }
        // repack [mlocal][col] bf16 then wide stores
#pragma unroll
        for (int fm = 0; fm < 2; fm++)
#pragma unroll
            for (int fn = 0; fn < 8; fn++)
#pragma unroll
                for (int rr = 0; rr < 4; rr++) {
                    int ml = w * 32 + fm * 16 + quad * 4 + rr;
                    smem[ml * 136 + fn * 16 + l15] = f2bf(acc[fm][fn][rr]);
                }
        __syncthreads();
        {
            int ml = t >> 1, seg = t & 1;
            u16* dst = qkv + ((size_t)b * 512 + mbase + ml) * 4096 + nbase + seg * 64;
#pragma unroll
            for (int i = 0; i < 8; i++) {
                uint4 u = *(const uint4*)&smem[ml * 136 + seg * 64 + i * 8];
                *(uint4*)(dst + i * 8) = u;
            }
        }
    } else {
        // v: transpose repack [col][mlocal] -> vT[b][n][d]
#pragma unroll
        for (int fm = 0; fm < 2; fm++)
#pragma unroll
            for (int fn = 0; fn < 8; fn++)
#pragma unroll
                for (int rr = 0; rr < 4; rr++) {
                    int ml = w * 32 + fm * 16 + quad * 4 + rr;
                    int col = fn * 16 + l15;
                    smem[col * 136 + ml] = f2bf(acc[fm][fn][rr]);
                }
        __syncthreads();
        {
            int nl = t >> 1, seg = t & 1;
            int dbase = mbase - 512;
            u16* dst = vT + ((size_t)b * 4096 + nbase + nl) * 256 + dbase + seg * 64;
#pragma unroll
            for (int i = 0; i < 8; i++) {
                uint4 u = *(const uint4*)&smem[nl * 136 + seg * 64 + i * 8];
                *(uint4*)(dst + i * 8) = u;
            }
        }
    }
}

// K4: raw sim = q.k^T, LDS-free (frags straight from global), K split x16, atomics. grid 2048.
__global__ __launch_bounds__(256) void k_sim(const u16* __restrict__ qkv, float* __restrict__ sims) {
    int bid = blockIdx.x;
    int kc = bid & 15, bh = bid >> 4;
    int b = bh >> 3, h = bh & 7;
    int t = threadIdx.x, w = t >> 6, lane = t & 63, l15 = lane & 15, quad = lane >> 4;
    int ib = w >> 1, jb = w & 1;
    const u16* qb = qkv + ((size_t)b * 512 + h * 32 + ib * 16 + l15) * 4096 + kc * 256 + quad * 8;
    const u16* kb = qkv + ((size_t)b * 512 + 256 + h * 32 + jb * 16 + l15) * 4096 + kc * 256 + quad * 8;
    f32x4 acc = {0.f, 0.f, 0.f, 0.f};
#pragma unroll
    for (int s = 0; s < 8; s++) {
        bf16x8 qf = *(const bf16x8*)(qb + s * 32);
        bf16x8 kf = *(const bf16x8*)(kb + s * 32);
        acc = MFMA(qf, kf, acc);
    }
    float* sp = sims + (size_t)bh * 1024;
#pragma unroll
    for (int rr = 0; rr < 4; rr++)
        atomicAdd(sp + (ib * 16 + quad * 4 + rr) * 32 + jb * 16 + l15, acc[rr]);
}

// K5: scale + softmax -> attn bf16 and attnT bf16. grid 128, block 64.
__global__ __launch_bounds__(64) void k_soft(const float* __restrict__ sims,
                                             const float* __restrict__ normsq,
                                             const float* __restrict__ temp,
                                             u16* __restrict__ attn, u16* __restrict__ attnT) {
    int bh = blockIdx.x;
    int b = bh >> 3, h = bh & 7;
    __shared__ float scq[32], sck[32];
    int t = threadIdx.x;
    if (t < 32)
        scq[t] = expf(temp[h]) * 8.0f / fmaxf(sqrtf(normsq[b * 512 + h * 32 + t]), 1e-12f);
    else {
        int d = t - 32;
        sck[d] = 1.0f / fmaxf(sqrtf(normsq[b * 512 + 256 + h * 32 + d]), 1e-12f);
    }
    __syncthreads();
    if (t < 32) {
        float row[32];
        float m = -1e30f;
        const float* sp = sims + (size_t)bh * 1024 + t * 32;
        float sq = scq[t];
        for (int j = 0; j < 32; j++) { float v = sp[j] * sq * sck[j]; row[j] = v; m = fmaxf(m, v); }
        float s = 0.f;
        for (int j = 0; j < 32; j++) { float p = expf(row[j] - m); row[j] = p; s += p; }
        float inv = 1.f / s;
        u16* ap = attn + (size_t)bh * 1024 + t * 32;
        u16* apT = attnT + (size_t)bh * 1024;
        for (int j = 0; j < 32; j++) {
            u16 hv = f2bf(row[j] * inv);
            ap[j] = hv;
            apT[j * 32 + t] = hv;  // attnT[j][d] = attn[d][j]
        }
    }
}

// K6: M2[b][c][h*32+j] = sum_d WoutT[c][h*32+d] * attn[d][j]. grid 128 (b*8+h).
__global__ __launch_bounds__(256) void k_m2(const u16* __restrict__ WoutT,
                                            const u16* __restrict__ attnT, u16* __restrict__ M2) {
    int bh = blockIdx.x;
    int b = bh >> 3, h = bh & 7;
    int t = threadIdx.x, w = t >> 6, lane = t & 63, l15 = lane & 15, quad = lane >> 4;
    const u16* at = attnT + (size_t)bh * 1024;
    bf16x8 bf0 = *(const bf16x8*)(at + l15 * 32 + quad * 8);         // j 0..15
    bf16x8 bf1 = *(const bf16x8*)(at + (16 + l15) * 32 + quad * 8);  // j 16..31
    f32x4 z = {0.f, 0.f, 0.f, 0.f};
#pragma unroll
    for (int fm = 0; fm < 4; fm++) {
        bf16x8 af = *(const bf16x8*)(WoutT + (size_t)(w * 64 + fm * 16 + l15) * 256 + h * 32 + quad * 8);
        f32x4 d0 = MFMA(af, bf0, z);
        f32x4 d1 = MFMA(af, bf1, z);
#pragma unroll
        for (int rr = 0; rr < 4; rr++) {
            int c = w * 64 + fm * 16 + quad * 4 + rr;
            u16* mp = M2 + ((size_t)b * 256 + c) * 256 + h * 32;
            mp[l15] = f2bf(d0[rr]);
            mp[16 + l15] = f2bf(d1[rr]);
        }
    }
}

// K7: out = M2[b] . v  (B = vT[b][n][k], A = M2 rows in registers), fp32 + bias. grid 1024.
__global__ __launch_bounds__(256, 3) void k_out(const u16* __restrict__ M2,
                                                const u16* __restrict__ vT,
                                                const float* __restrict__ bias,
                                                float* __restrict__ out) {
    int bid = blockIdx.x;
    int b = bid >> 6, r0 = bid & 63;
    int mt = r0 >> 5, nt = r0 & 31;
    int mbase = mt * 128, nbase = nt * 128;
    __shared__ __align__(16) u16 smem[128 * 136];
    float* smf = (float*)smem;  // [128][68] per n-half in epilogue
    int t = threadIdx.x, w = t >> 6, lane = t & 63, l15 = lane & 15, quad = lane >> 4;
    bf16x8 afr[2][8];
#pragma unroll
    for (int fm = 0; fm < 2; fm++)
#pragma unroll
        for (int kt = 0; kt < 8; kt++)
            afr[fm][kt] = *(const bf16x8*)(M2 + ((size_t)b * 256 + mbase + w * 32 + fm * 16 + l15) * 256 + kt * 32 + quad * 8);
    f32x4 acc[2][8];
    f32x4 z = {0.f, 0.f, 0.f, 0.f};
#pragma unroll
    for (int fm = 0; fm < 2; fm++)
#pragma unroll
        for (int fn = 0; fn < 8; fn++) acc[fm][fn] = z;
    const u16* Bp = vT + ((size_t)b * 4096 + nbase) * 256;
    int srow = t >> 1, sseg = t & 1;
    for (int h = 0; h < 2; h++) {
        if (h) __syncthreads();
#pragma unroll
        for (int g = 0; g < 2; g++) {
            uint4 ld[4];
#pragma unroll
            for (int i = 0; i < 4; i++)
                ld[i] = *(const uint4*)(Bp + (size_t)srow * 256 + h * 128 + sseg * 64 + g * 32 + i * 8);
#pragma unroll
            for (int i = 0; i < 4; i++)
                *(uint4*)&smem[srow * 136 + sseg * 64 + g * 32 + i * 8] = ld[i];
        }
        __syncthreads();
#pragma unroll
        for (int ktl = 0; ktl < 4; ktl++) {
            int kt = h * 4 + ktl;
#pragma unroll
            for (int fn = 0; fn < 8; fn++) {
                bf16x8 bfr = *(const bf16x8*)&smem[(fn * 16 + l15) * 136 + ktl * 32 + quad * 8];
                acc[0][fn] = MFMA(afr[0][kt], bfr, acc[0][fn]);
                acc[1][fn] = MFMA(afr[1][kt], bfr, acc[1][fn]);
            }
        }
    }
    // epilogue: two n-halves through LDS (f32), bias on readback, float4 stores
#pragma unroll
    for (int nh = 0; nh < 2; nh++) {
        __syncthreads();
#pragma unroll
        for (int fm = 0; fm < 2; fm++)
#pragma unroll
            for (int fnh = 0; fnh < 4; fnh++)
#pragma unroll
                for (int rr = 0; rr < 4; rr++) {
                    int ml = w * 32 + fm * 16 + quad * 4 + rr;
                    smf[ml * 68 + fnh * 16 + l15] = acc[fm][nh * 4 + fnh][rr];
                }
        __syncthreads();
        {
            int ml = t >> 1, seg = t & 1;
            float bs = bias[mbase + ml];
            float* dst = out + ((size_t)b * 256 + mbase + ml) * 4096 + nbase + nh * 64 + seg * 32;
#pragma unroll
            for (int i = 0; i < 8; i++) {
                float4 v = *(const float4*)&smf[ml * 68 + seg * 32 + i * 4];
                v.x += bs; v.y += bs; v.z += bs; v.w += bs;
                *(float4*)(dst + i * 4) = v;
            }
        }
    }
}

extern "C" void kernel_launch(void* const* d_in, const int* in_sizes, int n_in,
                              void* d_out, int out_size, void* d_ws, size_t ws_size,
                              hipStream_t stream) {
    const float* x     = (const float*)d_in[0];
    const float* gamma = (const float*)d_in[1];
    const float* beta  = (const float*)d_in[2];
    const float* Wqkv  = (const float*)d_in[3];
    const float* temp  = (const float*)d_in[4];
    const float* Wout  = (const float*)d_in[5];
    const float* bout  = (const float*)d_in[6];
    float* out = (float*)d_out;

    char* ws = (char*)d_ws;
    size_t off = 0;
    auto alloc = [&](size_t nbytes) -> void* {
        void* p = ws + off;
        off = (off + nbytes + 255) & ~(size_t)255;
        return p;
    };
    u16* xlnT     = (u16*)alloc((size_t)16 * 4096 * 256 * 2);   // 32 MB (b,n,c)
    u16* WqkvT    = (u16*)alloc((size_t)768 * 256 * 2);
    u16* WoutT    = (u16*)alloc((size_t)256 * 256 * 2);
    u16* qkv      = (u16*)alloc((size_t)16 * 512 * 4096 * 2);   // 64 MB (b, q/k rows, n)
    u16* vT       = (u16*)alloc((size_t)16 * 4096 * 256 * 2);   // 32 MB (b,n,d)
    float* normsq = (float*)alloc((size_t)16 * 512 * 4);
    float* sims   = (float*)alloc((size_t)128 * 1024 * 4);
    u16* attn     = (u16*)alloc((size_t)128 * 1024 * 2);
    u16* attnT    = (u16*)alloc((size_t)128 * 1024 * 2);
    u16* M2       = (u16*)alloc((size_t)16 * 256 * 256 * 2);    // 2 MB
    (void)ws_size; (void)in_sizes; (void)n_in; (void)out_size;

    hipLaunchKernelGGL(k_ln, dim3(1024), dim3(256), 0, stream, x, gamma, beta, xlnT);
    hipLaunchKernelGGL(k_prep, dim3(768), dim3(256), 0, stream, Wqkv, Wout, WqkvT, WoutT, sims, normsq);
    hipLaunchKernelGGL(k_qkv, dim3(3072), dim3(256), 0, stream, WqkvT, xlnT, qkv, vT, normsq);
    hipLaunchKernelGGL(k_sim, dim3(2048), dim3(256), 0, stream, qkv, sims);
    hipLaunchKernelGGL(k_soft, dim3(128), dim3(64), 0, stream, sims, normsq, temp, attn, attnT);
    hipLaunchKernelGGL(k_m2, dim3(128), dim3(256), 0, stream, WoutT, attnT, M2);
    hipLaunchKernelGGL(k_out, dim3(1024), dim3(256), 0, stream, M2, vT, bout, out);
}